// Round 1
// baseline (1124.905 us; speedup 1.0000x reference)
//
#include <hip/hip_runtime.h>
#include <math.h>

#define BB 16
#define CC 256
#define HH 64
#define WW 64
#define HWX (HH*WW)
#define KK 81
#define CCHUNK 16

// ---------------- K1: inverse L2 norms over channel dim ----------------
__global__ __launch_bounds__(256) void norm_kernel(
    const float* __restrict__ fA, const float* __restrict__ fB,
    float* __restrict__ invA, float* __restrict__ invB) {
    int id = blockIdx.x * blockDim.x + threadIdx.x;   // 0 .. 2*B*HW-1
    int isB = (id >= BB * HWX);
    int pix = isB ? (id - BB * HWX) : id;             // b*HW + h*W + w
    const float* src = isB ? fB : fA;
    int b = pix >> 12;          // /4096
    int hw = pix & (HWX - 1);
    const float* p = src + (size_t)b * CC * HWX + hw;
    float s = 0.f;
    #pragma unroll 8
    for (int c = 0; c < CC; ++c) {
        float v = p[(size_t)c * HWX];
        s += v * v;
    }
    float n = fmaxf(sqrtf(s), 1e-12f);
    float inv = 1.0f / n;
    (isB ? invB : invA)[pix] = inv;
}

// ---------------- K2: correlation, one block per (b, h) row ----------------
union SMem {
    struct {
        float Al[CCHUNK][WW];        // 4 KB
        float Bl[CCHUNK][9][WW + 8]; // 16*9*72*4 = 41.5 KB, w-padded by 4 each side
    } s;
    float red[KK][WW];               // 20.25 KB (used only after main loop)
};

__global__ __launch_bounds__(256) void corr_kernel(
    const float* __restrict__ fA, const float* __restrict__ fB,
    const float* __restrict__ invA, const float* __restrict__ invB,
    float* __restrict__ out) {
    __shared__ SMem sm;

    const int h = blockIdx.x;
    const int b = blockIdx.y;
    const int tid = threadIdx.x;
    const int w = tid & 63;
    const int wave = tid >> 6;

    // zero whole Bl once (pads stay zero across chunks; interior rewritten each chunk)
    for (int i = tid; i < CCHUNK * 9 * (WW + 8); i += 256)
        (&sm.s.Bl[0][0][0])[i] = 0.f;

    float acc[KK];
    #pragma unroll
    for (int k = 0; k < KK; ++k) acc[k] = 0.f;

    const float* Abase = fA + (size_t)b * CC * HWX + h * WW;

    for (int c0 = 0; c0 < CC; c0 += CCHUNK) {
        __syncthreads();   // previous compute (and zero-init) done before restaging
        // stage A chunk: CCHUNK x 64
        for (int i = tid; i < CCHUNK * WW; i += 256) {
            int cc = i >> 6, ww = i & 63;
            sm.s.Al[cc][ww] = Abase[(size_t)(c0 + cc) * HWX + ww];
        }
        // stage B chunk: CCHUNK x 9 rows x 64 (zero rows outside image)
        for (int i = tid; i < CCHUNK * 9 * WW; i += 256) {
            int ww = i & 63;
            int r  = i >> 6;         // 0..143
            int dy = r % 9;
            int cc = r / 9;
            int hb = h + dy - 4;
            float v = 0.f;
            if (hb >= 0 && hb < HH)
                v = fB[((size_t)b * CC + (c0 + cc)) * HWX + hb * WW + ww];
            sm.s.Bl[cc][dy][4 + ww] = v;
        }
        __syncthreads();
        // compute: wave v handles channels cc = wave*4 .. wave*4+3
        #pragma unroll
        for (int j = 0; j < 4; ++j) {
            int cc = wave * 4 + j;
            float a = sm.s.Al[cc][w];
            #pragma unroll
            for (int dy = 0; dy < 9; ++dy) {
                #pragma unroll
                for (int dx = 0; dx < 9; ++dx) {
                    float bv = sm.s.Bl[cc][dy][w + dx];   // pad handles halo
                    acc[dy * 9 + dx] += a * bv;
                }
            }
        }
    }

    // cross-wave reduction into sm.red
    __syncthreads();
    for (int v = 0; v < 4; ++v) {
        if (wave == v) {
            if (v == 0) {
                #pragma unroll
                for (int k = 0; k < KK; ++k) sm.red[k][w] = acc[k];
            } else {
                #pragma unroll
                for (int k = 0; k < KK; ++k) sm.red[k][w] += acc[k];
            }
        }
        __syncthreads();
    }

    // epilogue: normalize and store
    const float* iA = invA + b * HWX + h * WW;
    for (int idx = tid; idx < KK * WW; idx += 256) {
        int k  = idx >> 6;
        int ww = idx & 63;
        int dy = k / 9, dx = k % 9;
        int hb = h + dy - 4, wb = ww + dx - 4;
        float val = 0.f;
        if (hb >= 0 && hb < HH && wb >= 0 && wb < WW)
            val = sm.red[k][ww] * iA[ww] * invB[b * HWX + hb * WW + wb];
        out[(((size_t)b * KK + k) * HH + h) * WW + ww] = val;
    }
}

// ---------------- launcher ----------------
extern "C" void kernel_launch(void* const* d_in, const int* in_sizes, int n_in,
                              void* d_out, int out_size, void* d_ws, size_t ws_size,
                              hipStream_t stream) {
    const float* fA = (const float*)d_in[0];
    const float* fB = (const float*)d_in[1];
    float* outp = (float*)d_out;
    float* invA = (float*)d_ws;                 // B*H*W floats
    float* invB = invA + BB * HWX;              // B*H*W floats (total 512 KB of ws)

    norm_kernel<<<(2 * BB * HWX) / 256, 256, 0, stream>>>(fA, fB, invA, invB);
    corr_kernel<<<dim3(HH, BB), 256, 0, stream>>>(fA, fB, invA, invB, outp);
}

// Round 2
// 80.204 us; speedup vs baseline: 14.0255x; 14.0255x over previous
//
#include <hip/hip_runtime.h>
#include <math.h>

typedef short short8 __attribute__((ext_vector_type(8)));
typedef float f32x16 __attribute__((ext_vector_type(16)));

#define BB 16
#define CC 256
#define HH 64
#define WW 64
#define HWX 4096
#define DD 4
#define KD 9
#define KK 81

__device__ __forceinline__ unsigned short f2bf(float x) {
    union { float f; unsigned u; } v; v.f = x;
    unsigned r = v.u + 0x7FFFu + ((v.u >> 16) & 1u);   // RNE
    return (unsigned short)(r >> 16);
}

// Stage one (row of 64 w) x (256 c) fp32 plane into LDS bf16 [w][c] with XOR
// swizzle; also accumulate per-(wave,w) sum of squares into part[].
// Lane l owns w=l; wave wv owns c in [wv*64, wv*64+64).
__device__ __forceinline__ void stage_row(const float* __restrict__ src,
                                          unsigned short* lds, float* part,
                                          int wv, int l) {
    float ss = 0.f;
    const float* p = src + l;
    #pragma unroll
    for (int r = 0; r < 8; ++r) {
        const int c0 = wv * 64 + r * 8;
        float v[8];
        #pragma unroll
        for (int j = 0; j < 8; ++j) {
            v[j] = p[(size_t)(c0 + j) * HWX];
            ss += v[j] * v[j];
        }
        short8 st;
        #pragma unroll
        for (int j = 0; j < 8; ++j) st[j] = (short)f2bf(v[j]);
        int byte = l * 512 + c0 * 2;
        byte ^= (l & 7) << 4;                 // T2 swizzle
        *(short8*)((char*)lds + byte) = st;
    }
    part[wv * 64 + l] = ss;
}

__global__ __launch_bounds__(256) void corr_mfma(
    const float* __restrict__ fA, const float* __restrict__ fB,
    float* __restrict__ out)
{
    __shared__ __attribute__((aligned(16))) unsigned short Als[WW * CC]; // 32KB
    __shared__ __attribute__((aligned(16))) unsigned short Bls[WW * CC]; // 32KB
    __shared__ float red[KD][WW];        // banded outputs for one dy
    __shared__ float part[4 * WW];       // cross-wave sumsq partials
    __shared__ float invA_ls[WW], invB_ls[WW];

    // XCD-aware swizzle: 1024 blocks, 8 XCDs -> XCD x gets contiguous (b,h) chunk
    const int bid = blockIdx.x;
    const int swz = (bid & 7) * 128 + (bid >> 3);
    const int b = swz >> 6, h = swz & 63;

    const int tid = threadIdx.x;
    const int wv = tid >> 6, l = tid & 63;

    // ---- prologue: stage A row, compute invA, hoist A fragments ----
    const float* Abase = fA + (size_t)b * CC * HWX + h * WW;
    stage_row(Abase, Als, part, wv, l);
    __syncthreads();
    if (tid < WW) {
        float s = part[tid] + part[64 + tid] + part[128 + tid] + part[192 + tid];
        invA_ls[tid] = 1.f / fmaxf(sqrtf(s), 1e-12f);
    }
    __syncthreads();

    const int ti = wv >> 1, tj = wv & 1;     // wave quadrant of the 64x64 gram
    const int ml = l & 31, kg = l >> 5;
    const int m = ti * 32 + ml;              // A row (w)
    const int n = tj * 32 + ml;              // B row (w')

    short8 afr[16];
    #pragma unroll
    for (int s = 0; s < 16; ++s) {
        const int byte = (m * 512 + s * 32 + kg * 16) ^ ((m & 7) << 4);
        afr[s] = *(const short8*)((const char*)Als + byte);
    }

    // ---- loop over dy: stage B row, gram, band epilogue ----
    for (int dy = 0; dy < KD; ++dy) {
        const int hB = h + dy - DD;
        float* obase = out + (((size_t)b * KK + dy * KD) * HH + h) * WW;
        if (hB >= 0 && hB < HH) {
            stage_row(fB + (size_t)b * CC * HWX + (size_t)hB * WW, Bls, part, wv, l);
            __syncthreads();                                   // b1: Bls, part ready
            if (tid < WW) {
                float s = part[tid] + part[64 + tid] + part[128 + tid] + part[192 + tid];
                invB_ls[tid] = 1.f / fmaxf(sqrtf(s), 1e-12f);
            }
            for (int i = tid; i < KD * WW; i += 256) ((float*)red)[i] = 0.f;

            f32x16 acc0, acc1;
            #pragma unroll
            for (int i = 0; i < 16; ++i) { acc0[i] = 0.f; acc1[i] = 0.f; }
            #pragma unroll
            for (int s = 0; s < 16; s += 2) {
                const int byte0 = (n * 512 + s * 32 + kg * 16) ^ ((n & 7) << 4);
                const int byte1 = (n * 512 + (s + 1) * 32 + kg * 16) ^ ((n & 7) << 4);
                short8 bf0 = *(const short8*)((const char*)Bls + byte0);
                short8 bf1 = *(const short8*)((const char*)Bls + byte1);
                acc0 = __builtin_amdgcn_mfma_f32_32x32x16_bf16(afr[s], bf0, acc0, 0, 0, 0);
                acc1 = __builtin_amdgcn_mfma_f32_32x32x16_bf16(afr[s + 1], bf1, acc1, 0, 0, 0);
            }
            __syncthreads();                                   // b2: red zeroed, invB ready
            const float ibn = invB_ls[n];
            #pragma unroll
            for (int r = 0; r < 16; ++r) {
                // D layout (m74/m101): col = lane&31 (=w'), row = (r&3)+8*(r>>2)+4*kg
                const int w = ti * 32 + (r & 3) + 8 * (r >> 2) + 4 * kg;
                const int dx = n - w + 4;
                if (dx >= 0 && dx < KD)
                    red[dx][w] = (acc0[r] + acc1[r]) * invA_ls[w] * ibn;
            }
            __syncthreads();                                   // b3: red complete
            for (int i = tid; i < KD * WW; i += 256)
                obase[(size_t)(i >> 6) * HWX + (i & 63)] = ((float*)red)[i];
        } else {
            // whole dy-plane is zero padding; out is poisoned so must write
            for (int i = tid; i < KD * WW; i += 256)
                obase[(size_t)(i >> 6) * HWX + (i & 63)] = 0.f;
        }
    }
}

extern "C" void kernel_launch(void* const* d_in, const int* in_sizes, int n_in,
                              void* d_out, int out_size, void* d_ws, size_t ws_size,
                              hipStream_t stream) {
    const float* fA = (const float*)d_in[0];
    const float* fB = (const float*)d_in[1];
    float* outp = (float*)d_out;
    corr_mfma<<<dim3(BB * HH), 256, 0, stream>>>(fA, fB, outp);
}